// Round 14
// baseline (278.768 us; speedup 1.0000x reference)
//
#include <hip/hip_runtime.h>
#include <hip/hip_bf16.h>

// WaveNet dilated conv stack, MI355X gfx950. Round 14 (= round 13 + 2-tile blocks):
//  - every kernel processes tiles (2p, 2p+1): grid 512 = ONE co-resident
//    generation (no ragged tail), tile-1 staging prefetched under tile-0
//    epilogue (xs dead at issue point; next barrier drains vmcnt).
//  - tails: as_ disjoint from xs (prefetch safety); pairs unchanged r13 bodies.
//  - XCD-chunked swizzle: XCD k owns tiles [16k,16k+16) per batch (as r13).

#define CH 64
#define TLEN 16384
#define NB 8
#define BN 128
#define NLAYER 10

typedef __attribute__((ext_vector_type(4))) float f32x4;
typedef __attribute__((ext_vector_type(8))) short s16x8;
typedef __attribute__((ext_vector_type(4))) unsigned short u16x4;

__device__ __forceinline__ unsigned short f2bf(float f) {
    union { float f; unsigned u; } v; v.f = f;
    unsigned r = v.u + 0x7fffu + ((v.u >> 16) & 1u);  // RNE
    return (unsigned short)(r >> 16);
}
__device__ __forceinline__ float bf2f(unsigned short u) {
    union { unsigned u; float f; } v; v.u = ((unsigned)u) << 16;
    return v.f;
}
__device__ __forceinline__ void gload_lds16(const void* g, void* l) {
    __builtin_amdgcn_global_load_lds(
        (const __attribute__((address_space(1))) unsigned int*)g,
        (__attribute__((address_space(3))) unsigned int*)l, 16, 0, 0);
}
// 512-block bijective remap: XCD k owns pair-indices [8k,8k+8) -> tiles [16k,16k+16).
__device__ __forceinline__ void swz2(int& pi, int& b) {
    const int lin = blockIdx.y * 64 + blockIdx.x;
    const int xcd = lin & 7;
    const int idx = lin >> 3;
    pi = xcd * 8 + (idx & 7);
    b  = idx >> 3;
}

#define NCONV (NLAYER * 4 * 2 * 6 * 64 * 8)
#define NOUT  (NLAYER * 4 * 2 * 64 * 8)

__global__ void pack_weights(const float* __restrict__ wconv,
                             const float* __restrict__ wout,
                             unsigned short* __restrict__ wcpk,
                             unsigned short* __restrict__ wopk)
{
    int idx = blockIdx.x * 256 + threadIdx.x;
    if (idx < NCONV) {
        int j = idx & 7, t = idx >> 3;
        int lane = t & 63; t >>= 6;
        int ks = t % 6;   t /= 6;
        int m  = t & 1;   t >>= 1;
        int wv = t & 3;   int l = t >> 2;
        int o  = (m * 4 + wv) * 16 + (lane & 15);
        int ck = ks * 32 + (lane >> 4) * 8 + j;
        int kk = ck >> 6, c = ck & 63;
        wcpk[idx] = f2bf(wconv[(((size_t)l * 128 + o) * CH + c) * 3 + (2 - kk)]);
    } else if (idx < NCONV + NOUT) {
        int id = idx - NCONV;
        int j = id & 7, t = id >> 3;
        int lane = t & 63; t >>= 6;
        int ks = t & 1;    t >>= 1;
        int wv = t & 3;    int l = t >> 2;
        int o  = wv * 16 + (lane & 15);
        int c  = ks * 32 + (lane >> 4) * 8 + j;
        wopk[id] = f2bf(wout[((size_t)l * CH + o) * CH + c]);
    }
}

// ---------------- fused layer pair (I0, I0+1), dilations d, 2d, 2 tiles ----------------
template<int I0, bool SRC_F32>
__global__ __launch_bounds__(256, 4)
void wavenet_pair(const void* __restrict__ xin_,
                  unsigned short* __restrict__ xoutp,
                  float* __restrict__ out,
                  const unsigned short* __restrict__ wcpk,
                  const unsigned short* __restrict__ wopk,
                  const float* __restrict__ bconv,
                  const float* __restrict__ bout)
{
    constexpr int d   = 1 << I0;
    constexpr int D   = 2 * d;
    constexpr int TD  = 2 * D;
    constexpr int W1T = (128 + TD + 15) / 16;   // 9,9,12
    constexpr int W1  = W1T * 16;
    constexpr int WIN = W1 + 2 * d;

    __shared__ __align__(16) unsigned short xs[WIN * 64];
    __shared__ __align__(16) unsigned short ci[W1 * 64];
    __shared__ __align__(16) unsigned short as2[64 * 64];

    const int tid  = threadIdx.x;
    const int lane = tid & 63;
    const int wv   = tid >> 6;
    const int hrow = lane & 15;
    const int kgrp = lane >> 4;
    int pi, b;
    swz2(pi, b);
    const size_t xbase  = (size_t)b * CH * TLEN;
    const size_t planeF = (size_t)NB * CH * TLEN;
    const int o0 = wv * 16 + kgrp * 4;

    s16x8 w0[6], w1[6], wa2[2];
    float bt[4], bs[4], bo[4];
    auto loadw = [&](int L) {
        const unsigned short* bw = wcpk + ((size_t)(L * 4 + wv) * 768 + lane) * 8;
        #pragma unroll
        for (int ks = 0; ks < 6; ++ks) {
            w0[ks] = *reinterpret_cast<const s16x8*>(bw + (size_t)ks * 512);
            w1[ks] = *reinterpret_cast<const s16x8*>(bw + (size_t)(6 + ks) * 512);
        }
        const unsigned short* b2 = wopk + ((size_t)(L * 4 + wv) * 128 + lane) * 8;
        wa2[0] = *reinterpret_cast<const s16x8*>(b2);
        wa2[1] = *reinterpret_cast<const s16x8*>(b2 + 512);
        const float* Bc = bconv + (size_t)L * 128;
        const float* Bo = bout + (size_t)L * CH;
        #pragma unroll
        for (int r = 0; r < 4; ++r) {
            bt[r] = Bc[o0 + r];
            bs[r] = Bc[64 + o0 + r];
            bo[r] = Bo[o0 + r];
        }
    };

    auto stage_window = [&](int lo) {
        if (SRC_F32) {
            const float* x = (const float*)xin_;
            #pragma unroll
            for (int c8 = 0; c8 < 8; ++c8) {
                for (int q0 = tid; q0 < WIN; q0 += 256) {
                    const int tt = lo + q0;
                    s16x8 pk = {0, 0, 0, 0, 0, 0, 0, 0};
                    if (tt >= 0 && tt < TLEN) {
                        const float* pp = x + xbase + (size_t)(c8 * 8) * TLEN + tt;
                        #pragma unroll
                        for (int j = 0; j < 8; ++j) pk[j] = (short)f2bf(pp[(size_t)j * TLEN]);
                    }
                    *reinterpret_cast<s16x8*>(&xs[(size_t)(c8 * WIN + q0) * 8]) = pk;
                }
            }
        } else {
            const unsigned short* xb = (const unsigned short*)xin_ + xbase;
            constexpr int cnt = (WIN + 63) / 64;
            if (lo >= 0 && lo + WIN <= TLEN) {
                for (int task = wv; task < 8 * cnt; task += 4) {
                    const int c8 = task / cnt, n0 = (task % cnt) * 64;
                    const int rem = WIN - n0;
                    const unsigned short* sp = xb + (size_t)(lo + n0 + lane) * CH + c8 * 8;
                    unsigned short* dp = &xs[(size_t)(c8 * WIN + n0) * 8];
                    if (rem >= 64) gload_lds16(sp, dp);
                    else if (lane < rem) gload_lds16(sp, dp);
                }
            } else {
                for (int task = wv; task < 8 * cnt; task += 4) {
                    const int c8 = task / cnt, n0 = (task % cnt) * 64;
                    const int q0 = n0 + lane;
                    if (q0 < WIN) {
                        const int tt = lo + q0;
                        s16x8 pk = {0, 0, 0, 0, 0, 0, 0, 0};
                        if (tt >= 0 && tt < TLEN)
                            pk = *reinterpret_cast<const s16x8*>(xb + (size_t)tt * CH + c8 * 8);
                        *reinterpret_cast<s16x8*>(&xs[(size_t)(c8 * WIN + q0) * 8]) = pk;
                    }
                }
            }
        }
    };

    #pragma unroll 1
    for (int sub = 0; sub < 2; ++sub) {
        const int t0 = (2 * pi + sub) * BN;
        const int lo = t0 - 6 * d;
        if (sub == 0) stage_window(lo);
        loadw(I0);
        if (sub == 0) __syncthreads();   // sub1: end-of-loop barrier covers

        // ===== layer I0 over W1 cols (ci col q <-> t = t0 - TD + q) =====
        float* skipA = out + (size_t)(1 + I0) * planeF + xbase;
        #pragma unroll 1
        for (int c0 = 0; c0 < W1T; c0 += 3) {
            f32x4 aT[3], aS[3];
            #pragma unroll
            for (int i3 = 0; i3 < 3; ++i3) {
                aT[i3] = (f32x4){0.f, 0.f, 0.f, 0.f};
                aS[i3] = (f32x4){0.f, 0.f, 0.f, 0.f};
            }
            #pragma unroll
            for (int i3 = 0; i3 < 3; ++i3) {
                const int q = (c0 + i3) * 16 + hrow;
                #pragma unroll
                for (int ks = 0; ks < 6; ++ks) {
                    const int kb = ks * 4 + kgrp;
                    const int kk = kb >> 3, c8i = kb & 7;
                    const s16x8 bf = *reinterpret_cast<const s16x8*>(
                        &xs[(size_t)(c8i * WIN + q + (2 - kk) * d) * 8]);
                    aT[i3] = __builtin_amdgcn_mfma_f32_16x16x32_bf16(w0[ks], bf, aT[i3], 0, 0, 0);
                    aS[i3] = __builtin_amdgcn_mfma_f32_16x16x32_bf16(w1[ks], bf, aS[i3], 0, 0, 0);
                }
            }
            #pragma unroll
            for (int i3 = 0; i3 < 3; ++i3) {
                const int q = (c0 + i3) * 16 + hrow;
                #pragma unroll
                for (int r = 0; r < 4; ++r) {
                    const float yt = aT[i3][r] + bt[r];
                    const float ys = aS[i3][r] + bs[r];
                    const float th = 2.f * __builtin_amdgcn_rcpf(1.f + __expf(-2.f * yt)) - 1.f;
                    const float sg = __builtin_amdgcn_rcpf(1.f + __expf(-ys));
                    const float av = th * sg;
                    const int c = o0 + r;
                    if (q >= TD && q < TD + 128)
                        __builtin_nontemporal_store(av, &skipA[(size_t)c * TLEN + t0 + q - TD]);
                    ci[(size_t)((c >> 3) * W1 + q) * 8 + (c & 7)] = f2bf(av);
                }
            }
            __syncthreads();
            u16x4 stash[3];
            #pragma unroll
            for (int i3 = 0; i3 < 3; ++i3) {
                const int q = (c0 + i3) * 16 + hrow;
                f32x4 acc = (f32x4){0.f, 0.f, 0.f, 0.f};
                #pragma unroll
                for (int ks2 = 0; ks2 < 2; ++ks2) {
                    const s16x8 bf = *reinterpret_cast<const s16x8*>(
                        &ci[(size_t)((ks2 * 4 + kgrp) * W1 + q) * 8]);
                    acc = __builtin_amdgcn_mfma_f32_16x16x32_bf16(wa2[ks2], bf, acc, 0, 0, 0);
                }
                const u16x4 rv = *reinterpret_cast<const u16x4*>(
                    &xs[(size_t)((o0 >> 3) * WIN + q + 2 * d) * 8 + (o0 & 7)]);
                u16x4 ov;
                #pragma unroll
                for (int r = 0; r < 4; ++r)
                    ov[r] = (t0 + q >= TD) ? f2bf(acc[r] + bo[r] + bf2f(rv[r]))
                                           : (unsigned short)0;   // t<0: causal zero
                stash[i3] = ov;
            }
            __syncthreads();   // all 1x1 reads done before overwrite
            #pragma unroll
            for (int i3 = 0; i3 < 3; ++i3) {
                const int q = (c0 + i3) * 16 + hrow;
                *reinterpret_cast<u16x4*>(&ci[(size_t)((o0 >> 3) * W1 + q) * 8 + (o0 & 7)]) = stash[i3];
            }
        }
        __syncthreads();   // C_i complete; xs fully dead
        if (sub == 0) stage_window(lo + BN);   // prefetch tile1 window into xs

        // ===== layer I0+1 over 128 cols (t = t0 + n) =====
        loadw(I0 + 1);
        float* skipB = out + (size_t)(2 + I0) * planeF + xbase;
        unsigned short* xo = xoutp + xbase;

        #pragma unroll 1
        for (int hf = 0; hf < 2; ++hf) {
            f32x4 aT[4], aS[4];
            #pragma unroll
            for (int i4 = 0; i4 < 4; ++i4) {
                aT[i4] = (f32x4){0.f, 0.f, 0.f, 0.f};
                aS[i4] = (f32x4){0.f, 0.f, 0.f, 0.f};
            }
            #pragma unroll
            for (int i4 = 0; i4 < 4; ++i4) {
                const int n = (hf * 4 + i4) * 16 + hrow;
                #pragma unroll
                for (int ks = 0; ks < 6; ++ks) {
                    const int kb = ks * 4 + kgrp;
                    const int kk = kb >> 3, c8i = kb & 7;
                    const s16x8 bf = *reinterpret_cast<const s16x8*>(
                        &ci[(size_t)(c8i * W1 + n + (2 - kk) * D) * 8]);
                    aT[i4] = __builtin_amdgcn_mfma_f32_16x16x32_bf16(w0[ks], bf, aT[i4], 0, 0, 0);
                    aS[i4] = __builtin_amdgcn_mfma_f32_16x16x32_bf16(w1[ks], bf, aS[i4], 0, 0, 0);
                }
            }
            #pragma unroll
            for (int i4 = 0; i4 < 4; ++i4) {
                const int n = (hf * 4 + i4) * 16 + hrow;
                #pragma unroll
                for (int r = 0; r < 4; ++r) {
                    const float yt = aT[i4][r] + bt[r];
                    const float ys = aS[i4][r] + bs[r];
                    const float th = 2.f * __builtin_amdgcn_rcpf(1.f + __expf(-2.f * yt)) - 1.f;
                    const float sg = __builtin_amdgcn_rcpf(1.f + __expf(-ys));
                    const float av = th * sg;
                    const int c = o0 + r;
                    __builtin_nontemporal_store(av, &skipB[(size_t)c * TLEN + t0 + n]);
                    as2[(size_t)((c >> 3) * 64 + (n - hf * 64)) * 8 + (c & 7)] = f2bf(av);
                }
            }
            __syncthreads();
            #pragma unroll
            for (int i4 = 0; i4 < 4; ++i4) {
                const int n = (hf * 4 + i4) * 16 + hrow;
                const int nl = n - hf * 64;
                f32x4 acc = (f32x4){0.f, 0.f, 0.f, 0.f};
                #pragma unroll
                for (int ks2 = 0; ks2 < 2; ++ks2) {
                    const s16x8 bf = *reinterpret_cast<const s16x8*>(
                        &as2[(size_t)((ks2 * 4 + kgrp) * 64 + nl) * 8]);
                    acc = __builtin_amdgcn_mfma_f32_16x16x32_bf16(wa2[ks2], bf, acc, 0, 0, 0);
                }
                const u16x4 rv = *reinterpret_cast<const u16x4*>(
                    &ci[(size_t)((o0 >> 3) * W1 + n + TD) * 8 + (o0 & 7)]);
                u16x4 ov;
                #pragma unroll
                for (int r = 0; r < 4; ++r) ov[r] = f2bf(acc[r] + bo[r] + bf2f(rv[r]));
                *reinterpret_cast<u16x4*>(&xo[(size_t)(t0 + n) * CH + o0]) = ov;
            }
            __syncthreads();   // as2/ci reuse guard; final one also drains prefetch
        }
    }
}

// ------------- tail layers 6..9, 2 tiles/block -------------
// SM: 1 = single window NW=256 (L6, d=64), 2 = triple-tap (L7..9)
template<int SM, bool LAST>
__global__ __launch_bounds__(256, (SM == 2 && !LAST) ? 2 : 3)
void wavenet_tail(const unsigned short* __restrict__ xin, void* __restrict__ xout_,
                  float* __restrict__ skip,
                  const unsigned short* __restrict__ wcpk,
                  const unsigned short* __restrict__ wopk,
                  const float* __restrict__ bconv, const float* __restrict__ bout,
                  int layer, int dil)
{
    constexpr int XSN = (SM == 1) ? (8 * 256 * 8) : (24 * BN * 8);
    __shared__ __align__(16) unsigned short xs[XSN];               // 32 / 48 KB
    __shared__ __align__(16) unsigned short as_[LAST ? 16 : (8 * BN * 8)];  // 16 KB, DISJOINT

    const int tid  = threadIdx.x;
    const int lane = tid & 63;
    const int wv   = tid >> 6;
    const int hrow = lane & 15;
    const int kgrp = lane >> 4;
    int pi, b;
    swz2(pi, b);
    const size_t xbase = (size_t)b * CH * TLEN;
    const unsigned short* xb = xin + xbase;
    const int o0 = wv * 16 + kgrp * 4;

    s16x8 w0[6], w1[6], wa2[2];
    {
        const unsigned short* bw = wcpk + ((size_t)(layer * 4 + wv) * 768 + lane) * 8;
        #pragma unroll
        for (int ks = 0; ks < 6; ++ks) {
            w0[ks] = *reinterpret_cast<const s16x8*>(bw + (size_t)ks * 512);
            w1[ks] = *reinterpret_cast<const s16x8*>(bw + (size_t)(6 + ks) * 512);
        }
        const unsigned short* b2 = wopk + ((size_t)(layer * 4 + wv) * 128 + lane) * 8;
        wa2[0] = *reinterpret_cast<const s16x8*>(b2);
        wa2[1] = *reinterpret_cast<const s16x8*>(b2 + 512);
    }
    const float* Bc = bconv + (size_t)layer * 128;
    const float* Bo = bout + (size_t)layer * CH;
    float bt[4], bs[4], bo[4];
    #pragma unroll
    for (int r = 0; r < 4; ++r) {
        bt[r] = Bc[o0 + r];
        bs[r] = Bc[64 + o0 + r];
        bo[r] = Bo[o0 + r];
    }

    auto stage = [&](int t0) {
        if (SM == 1) {
            if (t0 >= 128) {
                for (int task = wv; task < 32; task += 4) {
                    const int c8 = task >> 2, n0 = (task & 3) * 64;
                    gload_lds16(xb + (size_t)(t0 - 128 + n0 + lane) * CH + c8 * 8,
                                &xs[(size_t)(c8 * 256 + n0) * 8]);
                }
            } else {
                for (int task = wv; task < 32; task += 4) {
                    const int c8 = task >> 2, n0 = (task & 3) * 64;
                    const int tg = t0 - 128 + n0 + lane;
                    s16x8 pk = {0, 0, 0, 0, 0, 0, 0, 0};
                    if (tg >= 0)
                        pk = *reinterpret_cast<const s16x8*>(xb + (size_t)tg * CH + c8 * 8);
                    *reinterpret_cast<s16x8*>(&xs[(size_t)(c8 * 256 + n0 + lane) * 8]) = pk;
                }
            }
        } else {
            if (t0 >= 2 * dil) {
                for (int ch = wv; ch < 48; ch += 4) {
                    const int kk = ch >> 4, c8 = (ch >> 1) & 7, n0 = (ch & 1) * 64;
                    gload_lds16(xb + (size_t)(t0 + n0 + lane - kk * dil) * CH + c8 * 8,
                                &xs[(size_t)((kk * 8 + c8) * BN + n0) * 8]);
                }
            } else {
                for (int ch = wv; ch < 48; ch += 4) {
                    const int kk = ch >> 4, c8 = (ch >> 1) & 7, n0 = (ch & 1) * 64;
                    const int tg = t0 + n0 + lane - kk * dil;
                    s16x8 pk = {0, 0, 0, 0, 0, 0, 0, 0};
                    if (tg >= 0)
                        pk = *reinterpret_cast<const s16x8*>(xb + (size_t)tg * CH + c8 * 8);
                    *reinterpret_cast<s16x8*>(&xs[(size_t)((kk * 8 + c8) * BN + n0 + lane) * 8]) = pk;
                }
            }
        }
    };

    #pragma unroll 1
    for (int sub = 0; sub < 2; ++sub) {
        const int t0 = (2 * pi + sub) * BN;
        if (sub == 0) { stage(t0); __syncthreads(); }

        // ---- conv MFMA ----
        f32x4 accT[8], accS[8];
        #pragma unroll
        for (int nt = 0; nt < 8; ++nt) {
            accT[nt] = (f32x4){0.f, 0.f, 0.f, 0.f};
            accS[nt] = (f32x4){0.f, 0.f, 0.f, 0.f};
        }
        #pragma unroll
        for (int nt = 0; nt < 8; ++nt) {
            #pragma unroll
            for (int ks = 0; ks < 6; ++ks) {
                const int kb = ks * 4 + kgrp;
                const unsigned short* bp;
                if (SM == 2) {
                    bp = &xs[(size_t)(kb * BN + nt * 16 + hrow) * 8];
                } else {
                    const int kk = kb >> 3, c8i = kb & 7;
                    bp = &xs[(size_t)(c8i * 256 + nt * 16 + hrow + (2 - kk) * dil) * 8];
                }
                const s16x8 bf = *reinterpret_cast<const s16x8*>(bp);
                accT[nt] = __builtin_amdgcn_mfma_f32_16x16x32_bf16(w0[ks], bf, accT[nt], 0, 0, 0);
                accS[nt] = __builtin_amdgcn_mfma_f32_16x16x32_bf16(w1[ks], bf, accS[nt], 0, 0, 0);
            }
        }
        u16x4 rvL[8];
        if (LAST) {
            #pragma unroll
            for (int nt = 0; nt < 8; ++nt)
                rvL[nt] = *reinterpret_cast<const u16x4*>(
                    &xs[(size_t)((o0 >> 3) * BN + nt * 16 + hrow) * 8 + (o0 & 7)]);
        }
        __syncthreads();                 // all xs reads done
        if (sub == 0) stage(t0 + BN);    // prefetch tile1 (drains at next barrier)

        // ---- act + skip (+ LAST final) ----
        #pragma unroll
        for (int nt = 0; nt < 8; ++nt) {
            const int n = nt * 16 + hrow;
            #pragma unroll
            for (int r = 0; r < 4; ++r) {
                const float yt = accT[nt][r] + bt[r];
                const float ys = accS[nt][r] + bs[r];
                const float th = 2.f * __builtin_amdgcn_rcpf(1.f + __expf(-2.f * yt)) - 1.f;
                const float sg = __builtin_amdgcn_rcpf(1.f + __expf(-ys));
                const float av = th * sg;
                const int c = o0 + r;
                __builtin_nontemporal_store(av, &skip[xbase + (size_t)c * TLEN + t0 + n]);
                if (LAST) {
                    __builtin_nontemporal_store(av + bf2f(rvL[nt][r]),
                        &((float*)xout_)[xbase + (size_t)c * TLEN + t0 + n]);
                } else {
                    as_[(size_t)((c >> 3) * BN + n) * 8 + (c & 7)] = f2bf(av);
                }
            }
        }
        if (!LAST) {
            __syncthreads();             // as_ ready (also drains prefetch)
            unsigned short* xo = (unsigned short*)xout_ + xbase;
            #pragma unroll
            for (int nt = 0; nt < 8; ++nt) {
                const int n = nt * 16 + hrow;
                f32x4 acc = (f32x4){0.f, 0.f, 0.f, 0.f};
                #pragma unroll
                for (int ks = 0; ks < 2; ++ks) {
                    const s16x8 bf = *reinterpret_cast<const s16x8*>(
                        &as_[(size_t)((ks * 4 + kgrp) * BN + n) * 8]);
                    acc = __builtin_amdgcn_mfma_f32_16x16x32_bf16(wa2[ks], bf, acc, 0, 0, 0);
                }
                const u16x4 rv = *reinterpret_cast<const u16x4*>(xb + (size_t)(t0 + n) * CH + o0);
                u16x4 ov;
                #pragma unroll
                for (int r = 0; r < 4; ++r) ov[r] = f2bf(acc[r] + bo[r] + bf2f(rv[r]));
                *reinterpret_cast<u16x4*>(&xo[(size_t)(t0 + n) * CH + o0]) = ov;
            }
        }
        __syncthreads();                 // as_/xs reuse guard; drains prefetch (LAST path)
    }
}

extern "C" void kernel_launch(void* const* d_in, const int* in_sizes, int n_in,
                              void* d_out, int out_size, void* d_ws, size_t ws_size,
                              hipStream_t stream)
{
    const float* x  = (const float*)d_in[0];
    const float* wc = (const float*)d_in[1];
    const float* bc = (const float*)d_in[2];
    const float* wo = (const float*)d_in[3];
    const float* bo = (const float*)d_in[4];
    float* out = (float*)d_out;
    const size_t planeF = (size_t)NB * CH * TLEN;

    unsigned short* PA = (unsigned short*)d_ws;
    unsigned short* PB = PA + planeF;
    unsigned short* wcpk = PB + planeF;
    unsigned short* wopk = wcpk + NCONV;

    pack_weights<<<(NCONV + NOUT) / 256, 256, 0, stream>>>(wc, wo, wcpk, wopk);

    dim3 grid2(64, NB), block(256);

    // fused pairs: (0,1) fp32 input -> PA ; (2,3) PA -> PB ; (4,5) PB -> PA
    wavenet_pair<0, true ><<<grid2, block, 0, stream>>>(x,  PA, out, wcpk, wopk, bc, bo);
    wavenet_pair<2, false><<<grid2, block, 0, stream>>>(PA, PB, out, wcpk, wopk, bc, bo);
    wavenet_pair<4, false><<<grid2, block, 0, stream>>>(PB, PA, out, wcpk, wopk, bc, bo);

    // tails: L6 (SM1), L7/L8 (SM2), L9 (SM2, LAST -> out slot 0)
    wavenet_tail<1, false><<<grid2, block, 0, stream>>>(
        PA, PB, out + 7 * planeF, wcpk, wopk, bc, bo, 6, 64);
    wavenet_tail<2, false><<<grid2, block, 0, stream>>>(
        PB, PA, out + 8 * planeF, wcpk, wopk, bc, bo, 7, 128);
    wavenet_tail<2, false><<<grid2, block, 0, stream>>>(
        PA, PB, out + 9 * planeF, wcpk, wopk, bc, bo, 8, 256);
    wavenet_tail<2, true><<<grid2, block, 0, stream>>>(
        PB, out, out + 10 * planeF, wcpk, wopk, bc, bo, 9, 512);
}

// Round 15
// 225.829 us; speedup vs baseline: 1.2344x; 1.2344x over previous
//
#include <hip/hip_runtime.h>
#include <hip/hip_bf16.h>

// WaveNet dilated conv stack, MI355X gfx950. Round 15 = round 13 verbatim
// (empirical best: 226 us). Pairs (0,1),(2,3),(4,5) fused block-locally with
// halo recompute; tails 6-9 per-layer; XCD-chunked block swizzle (taps L2-local);
// nontemporal skip/final stores. r14's 2-tile-per-block variant regressed
// (TLP halved); this locks in the best-known configuration.

#define CH 64
#define TLEN 16384
#define NB 8
#define BN 128
#define NLAYER 10

typedef __attribute__((ext_vector_type(4))) float f32x4;
typedef __attribute__((ext_vector_type(8))) short s16x8;
typedef __attribute__((ext_vector_type(4))) unsigned short u16x4;

__device__ __forceinline__ unsigned short f2bf(float f) {
    union { float f; unsigned u; } v; v.f = f;
    unsigned r = v.u + 0x7fffu + ((v.u >> 16) & 1u);  // RNE
    return (unsigned short)(r >> 16);
}
__device__ __forceinline__ float bf2f(unsigned short u) {
    union { unsigned u; float f; } v; v.u = ((unsigned)u) << 16;
    return v.f;
}
__device__ __forceinline__ void gload_lds16(const void* g, void* l) {
    __builtin_amdgcn_global_load_lds(
        (const __attribute__((address_space(1))) unsigned int*)g,
        (__attribute__((address_space(3))) unsigned int*)l, 16, 0, 0);
}
// Bijective XCD-chunked remap: XCD k gets tiles [16k,16k+16) for every batch.
__device__ __forceinline__ void swz_tile_b(int& tile, int& b) {
    const int lin = blockIdx.y * 128 + blockIdx.x;
    const int xcd = lin & 7;
    const int idx = lin >> 3;
    tile = xcd * 16 + (idx & 15);
    b    = idx >> 4;
}

#define NCONV (NLAYER * 4 * 2 * 6 * 64 * 8)
#define NOUT  (NLAYER * 4 * 2 * 64 * 8)

__global__ void pack_weights(const float* __restrict__ wconv,
                             const float* __restrict__ wout,
                             unsigned short* __restrict__ wcpk,
                             unsigned short* __restrict__ wopk)
{
    int idx = blockIdx.x * 256 + threadIdx.x;
    if (idx < NCONV) {
        int j = idx & 7, t = idx >> 3;
        int lane = t & 63; t >>= 6;
        int ks = t % 6;   t /= 6;
        int m  = t & 1;   t >>= 1;
        int wv = t & 3;   int l = t >> 2;
        int o  = (m * 4 + wv) * 16 + (lane & 15);
        int ck = ks * 32 + (lane >> 4) * 8 + j;
        int kk = ck >> 6, c = ck & 63;
        wcpk[idx] = f2bf(wconv[(((size_t)l * 128 + o) * CH + c) * 3 + (2 - kk)]);
    } else if (idx < NCONV + NOUT) {
        int id = idx - NCONV;
        int j = id & 7, t = id >> 3;
        int lane = t & 63; t >>= 6;
        int ks = t & 1;    t >>= 1;
        int wv = t & 3;    int l = t >> 2;
        int o  = wv * 16 + (lane & 15);
        int c  = ks * 32 + (lane >> 4) * 8 + j;
        wopk[id] = f2bf(wout[((size_t)l * CH + o) * CH + c]);
    }
}

// ---------------- fused layer pair (I0, I0+1), dilations d, 2d ----------------
template<int I0, bool SRC_F32>
__global__ __launch_bounds__(256, 4)
void wavenet_pair(const void* __restrict__ xin_,
                  unsigned short* __restrict__ xoutp,
                  float* __restrict__ out,
                  const unsigned short* __restrict__ wcpk,
                  const unsigned short* __restrict__ wopk,
                  const float* __restrict__ bconv,
                  const float* __restrict__ bout)
{
    constexpr int d   = 1 << I0;
    constexpr int D   = 2 * d;            // dilation of layer I0+1
    constexpr int TD  = 2 * D;            // 4d: halo of layer I0+1
    constexpr int W1T = (128 + TD + 15) / 16;   // tiles of C_i: 9,9,12
    constexpr int W1  = W1T * 16;
    constexpr int WIN = W1 + 2 * d;       // staged C_{i-1} cols

    __shared__ __align__(16) unsigned short xs[WIN * 64];   // C_{i-1} window
    __shared__ __align__(16) unsigned short ci[W1 * 64];    // act then C_i
    __shared__ __align__(16) unsigned short as2[64 * 64];   // layer i+1 1x1 staging

    const int tid  = threadIdx.x;
    const int lane = tid & 63;
    const int wv   = tid >> 6;
    const int hrow = lane & 15;
    const int kgrp = lane >> 4;
    int tile, b;
    swz_tile_b(tile, b);
    const int t0 = tile * BN;
    const size_t xbase  = (size_t)b * CH * TLEN;
    const size_t planeF = (size_t)NB * CH * TLEN;
    const int o0 = wv * 16 + kgrp * 4;
    const int lo = t0 - 6 * d;            // global t of xs col 0

    // ---- stage C_{i-1} window ----
    if (SRC_F32) {
        const float* x = (const float*)xin_;
        #pragma unroll
        for (int c8 = 0; c8 < 8; ++c8) {
            for (int p = tid; p < WIN; p += 256) {
                const int tt = lo + p;
                s16x8 pk = {0, 0, 0, 0, 0, 0, 0, 0};
                if (tt >= 0 && tt < TLEN) {
                    const float* pp = x + xbase + (size_t)(c8 * 8) * TLEN + tt;
                    #pragma unroll
                    for (int j = 0; j < 8; ++j) pk[j] = (short)f2bf(pp[(size_t)j * TLEN]);
                }
                *reinterpret_cast<s16x8*>(&xs[(size_t)(c8 * WIN + p) * 8]) = pk;
            }
        }
    } else {
        const unsigned short* xb = (const unsigned short*)xin_ + xbase;
        constexpr int cnt = (WIN + 63) / 64;
        if (lo >= 0 && lo + WIN <= TLEN) {
            for (int task = wv; task < 8 * cnt; task += 4) {
                const int c8 = task / cnt, n0 = (task % cnt) * 64;
                const int rem = WIN - n0;
                const unsigned short* sp = xb + (size_t)(lo + n0 + lane) * CH + c8 * 8;
                unsigned short* dp = &xs[(size_t)(c8 * WIN + n0) * 8];
                if (rem >= 64) gload_lds16(sp, dp);
                else if (lane < rem) gload_lds16(sp, dp);
            }
        } else {
            for (int task = wv; task < 8 * cnt; task += 4) {
                const int c8 = task / cnt, n0 = (task % cnt) * 64;
                const int p = n0 + lane;
                if (p < WIN) {
                    const int tt = lo + p;
                    s16x8 pk = {0, 0, 0, 0, 0, 0, 0, 0};
                    if (tt >= 0 && tt < TLEN)
                        pk = *reinterpret_cast<const s16x8*>(xb + (size_t)tt * CH + c8 * 8);
                    *reinterpret_cast<s16x8*>(&xs[(size_t)(c8 * WIN + p) * 8]) = pk;
                }
            }
        }
    }

    s16x8 w0[6], w1[6], wa2[2];
    float bt[4], bs[4], bo[4];
    auto loadw = [&](int L) {
        const unsigned short* bw = wcpk + ((size_t)(L * 4 + wv) * 768 + lane) * 8;
        #pragma unroll
        for (int ks = 0; ks < 6; ++ks) {
            w0[ks] = *reinterpret_cast<const s16x8*>(bw + (size_t)ks * 512);
            w1[ks] = *reinterpret_cast<const s16x8*>(bw + (size_t)(6 + ks) * 512);
        }
        const unsigned short* b2 = wopk + ((size_t)(L * 4 + wv) * 128 + lane) * 8;
        wa2[0] = *reinterpret_cast<const s16x8*>(b2);
        wa2[1] = *reinterpret_cast<const s16x8*>(b2 + 512);
        const float* Bc = bconv + (size_t)L * 128;
        const float* Bo = bout + (size_t)L * CH;
        #pragma unroll
        for (int r = 0; r < 4; ++r) {
            bt[r] = Bc[o0 + r];
            bs[r] = Bc[64 + o0 + r];
            bo[r] = Bo[o0 + r];
        }
    };

    loadw(I0);
    __syncthreads();

    // ================= layer I0 over W1 cols (ci col q <-> t = t0 - TD + q) =================
    float* skipA = out + (size_t)(1 + I0) * planeF + xbase;
    #pragma unroll 1
    for (int c0 = 0; c0 < W1T; c0 += 3) {
        f32x4 aT[3], aS[3];
        #pragma unroll
        for (int i3 = 0; i3 < 3; ++i3) {
            aT[i3] = (f32x4){0.f, 0.f, 0.f, 0.f};
            aS[i3] = (f32x4){0.f, 0.f, 0.f, 0.f};
        }
        #pragma unroll
        for (int i3 = 0; i3 < 3; ++i3) {
            const int q = (c0 + i3) * 16 + hrow;
            #pragma unroll
            for (int ks = 0; ks < 6; ++ks) {
                const int kb = ks * 4 + kgrp;
                const int kk = kb >> 3, c8i = kb & 7;
                const s16x8 bf = *reinterpret_cast<const s16x8*>(
                    &xs[(size_t)(c8i * WIN + q + (2 - kk) * d) * 8]);
                aT[i3] = __builtin_amdgcn_mfma_f32_16x16x32_bf16(w0[ks], bf, aT[i3], 0, 0, 0);
                aS[i3] = __builtin_amdgcn_mfma_f32_16x16x32_bf16(w1[ks], bf, aS[i3], 0, 0, 0);
            }
        }
        #pragma unroll
        for (int i3 = 0; i3 < 3; ++i3) {
            const int q = (c0 + i3) * 16 + hrow;
            #pragma unroll
            for (int r = 0; r < 4; ++r) {
                const float yt = aT[i3][r] + bt[r];
                const float ys = aS[i3][r] + bs[r];
                const float th = 2.f * __builtin_amdgcn_rcpf(1.f + __expf(-2.f * yt)) - 1.f;
                const float sg = __builtin_amdgcn_rcpf(1.f + __expf(-ys));
                const float av = th * sg;
                const int c = o0 + r;
                if (q >= TD && q < TD + 128)
                    __builtin_nontemporal_store(av, &skipA[(size_t)c * TLEN + t0 + q - TD]);
                ci[(size_t)((c >> 3) * W1 + q) * 8 + (c & 7)] = f2bf(av);
            }
        }
        __syncthreads();
        u16x4 stash[3];
        #pragma unroll
        for (int i3 = 0; i3 < 3; ++i3) {
            const int q = (c0 + i3) * 16 + hrow;
            f32x4 acc = (f32x4){0.f, 0.f, 0.f, 0.f};
            #pragma unroll
            for (int ks2 = 0; ks2 < 2; ++ks2) {
                const s16x8 bf = *reinterpret_cast<const s16x8*>(
                    &ci[(size_t)((ks2 * 4 + kgrp) * W1 + q) * 8]);
                acc = __builtin_amdgcn_mfma_f32_16x16x32_bf16(wa2[ks2], bf, acc, 0, 0, 0);
            }
            const u16x4 rv = *reinterpret_cast<const u16x4*>(
                &xs[(size_t)((o0 >> 3) * WIN + q + 2 * d) * 8 + (o0 & 7)]);
            u16x4 ov;
            #pragma unroll
            for (int r = 0; r < 4; ++r)
                ov[r] = (t0 + q >= TD) ? f2bf(acc[r] + bo[r] + bf2f(rv[r]))
                                       : (unsigned short)0;   // t<0: causal zero
            stash[i3] = ov;
        }
        __syncthreads();   // all 1x1 reads of this chunk done before overwrite
        #pragma unroll
        for (int i3 = 0; i3 < 3; ++i3) {
            const int q = (c0 + i3) * 16 + hrow;
            *reinterpret_cast<u16x4*>(&ci[(size_t)((o0 >> 3) * W1 + q) * 8 + (o0 & 7)]) = stash[i3];
        }
    }
    __syncthreads();   // C_i complete in ci

    // ================= layer I0+1 over 128 cols (t = t0 + n) =================
    loadw(I0 + 1);
    float* skipB = out + (size_t)(2 + I0) * planeF + xbase;
    unsigned short* xo = xoutp + xbase;

    #pragma unroll 1
    for (int hf = 0; hf < 2; ++hf) {
        f32x4 aT[4], aS[4];
        #pragma unroll
        for (int i4 = 0; i4 < 4; ++i4) {
            aT[i4] = (f32x4){0.f, 0.f, 0.f, 0.f};
            aS[i4] = (f32x4){0.f, 0.f, 0.f, 0.f};
        }
        #pragma unroll
        for (int i4 = 0; i4 < 4; ++i4) {
            const int n = (hf * 4 + i4) * 16 + hrow;
            #pragma unroll
            for (int ks = 0; ks < 6; ++ks) {
                const int kb = ks * 4 + kgrp;
                const int kk = kb >> 3, c8i = kb & 7;
                const s16x8 bf = *reinterpret_cast<const s16x8*>(
                    &ci[(size_t)(c8i * W1 + n + (2 - kk) * D) * 8]);
                aT[i4] = __builtin_amdgcn_mfma_f32_16x16x32_bf16(w0[ks], bf, aT[i4], 0, 0, 0);
                aS[i4] = __builtin_amdgcn_mfma_f32_16x16x32_bf16(w1[ks], bf, aS[i4], 0, 0, 0);
            }
        }
        #pragma unroll
        for (int i4 = 0; i4 < 4; ++i4) {
            const int n = (hf * 4 + i4) * 16 + hrow;
            #pragma unroll
            for (int r = 0; r < 4; ++r) {
                const float yt = aT[i4][r] + bt[r];
                const float ys = aS[i4][r] + bs[r];
                const float th = 2.f * __builtin_amdgcn_rcpf(1.f + __expf(-2.f * yt)) - 1.f;
                const float sg = __builtin_amdgcn_rcpf(1.f + __expf(-ys));
                const float av = th * sg;
                const int c = o0 + r;
                __builtin_nontemporal_store(av, &skipB[(size_t)c * TLEN + t0 + n]);
                as2[(size_t)((c >> 3) * 64 + (n - hf * 64)) * 8 + (c & 7)] = f2bf(av);
            }
        }
        __syncthreads();
        #pragma unroll
        for (int i4 = 0; i4 < 4; ++i4) {
            const int n = (hf * 4 + i4) * 16 + hrow;
            const int nl = n - hf * 64;
            f32x4 acc = (f32x4){0.f, 0.f, 0.f, 0.f};
            #pragma unroll
            for (int ks2 = 0; ks2 < 2; ++ks2) {
                const s16x8 bf = *reinterpret_cast<const s16x8*>(
                    &as2[(size_t)((ks2 * 4 + kgrp) * 64 + nl) * 8]);
                acc = __builtin_amdgcn_mfma_f32_16x16x32_bf16(wa2[ks2], bf, acc, 0, 0, 0);
            }
            const u16x4 rv = *reinterpret_cast<const u16x4*>(
                &ci[(size_t)((o0 >> 3) * W1 + n + TD) * 8 + (o0 & 7)]);
            u16x4 ov;
            #pragma unroll
            for (int r = 0; r < 4; ++r) ov[r] = f2bf(acc[r] + bo[r] + bf2f(rv[r]));
            *reinterpret_cast<u16x4*>(&xo[(size_t)(t0 + n) * CH + o0]) = ov;
        }
        __syncthreads();   // as2 reuse guard
    }
}

// ------------- tail layers 6..9 -------------
// SM: 1 = bf16 [T][C] single window (dil<=64), 2 = bf16 [T][C] triple-tap
template<int SM, bool LAST>
__global__ __launch_bounds__(256, 3)
void wavenet_layer(const void* __restrict__ xin_, void* __restrict__ xout_,
                   float* __restrict__ skip,
                   const unsigned short* __restrict__ wcpk,
                   const unsigned short* __restrict__ wopk,
                   const float* __restrict__ bconv, const float* __restrict__ bout,
                   int layer, int dil)
{
    extern __shared__ __align__(16) unsigned short xs[];
    unsigned short* as_ = xs;

    const int tid  = threadIdx.x;
    const int lane = tid & 63;
    const int wv   = tid >> 6;
    const int hrow = lane & 15;
    const int kgrp = lane >> 4;
    int tile, b;
    swz_tile_b(tile, b);
    const int t0 = tile * BN;
    const int NW = BN + 2 * dil;
    const size_t xbase = (size_t)b * CH * TLEN;

    if (SM == 1) {
        const unsigned short* xin = (const unsigned short*)xin_;
        const int cnt_n = (NW + 63) >> 6;
        if (t0 >= 2 * dil) {
            for (int ch = wv; ch < 8 * cnt_n; ch += 4) {
                const int c8 = ch / cnt_n;
                const int n0 = (ch % cnt_n) * 64;
                const int rem = NW - n0;
                const unsigned short* src =
                    xin + xbase + (size_t)(t0 - 2 * dil + n0 + lane) * CH + c8 * 8;
                unsigned short* dst = &xs[(size_t)(c8 * NW + n0) * 8];
                if (rem >= 64) gload_lds16(src, dst);
                else if (lane < rem) gload_lds16(src, dst);
            }
        } else {
            for (int ch = wv; ch < 8 * cnt_n; ch += 4) {
                const int c8 = ch / cnt_n;
                const int n0 = (ch % cnt_n) * 64;
                if (n0 + lane < NW) {
                    const int tg = t0 - 2 * dil + n0 + lane;
                    s16x8 pk = {0, 0, 0, 0, 0, 0, 0, 0};
                    if (tg >= 0)
                        pk = *reinterpret_cast<const s16x8*>(xin + xbase + (size_t)tg * CH + c8 * 8);
                    *reinterpret_cast<s16x8*>(&xs[(size_t)(c8 * NW + n0 + lane) * 8]) = pk;
                }
            }
        }
    } else {
        const unsigned short* xin = (const unsigned short*)xin_;
        if (t0 >= 2 * dil) {
            for (int ch = wv; ch < 48; ch += 4) {
                const int kk = ch >> 4, c8 = (ch >> 1) & 7, n0 = (ch & 1) * 64;
                const unsigned short* src =
                    xin + xbase + (size_t)(t0 + n0 + lane - kk * dil) * CH + c8 * 8;
                unsigned short* dst = &xs[(size_t)((kk * 8 + c8) * BN + n0) * 8];
                gload_lds16(src, dst);
            }
        } else {
            for (int ch = wv; ch < 48; ch += 4) {
                const int kk = ch >> 4, c8 = (ch >> 1) & 7, n0 = (ch & 1) * 64;
                const int tg = t0 + n0 + lane - kk * dil;
                s16x8 pk = {0, 0, 0, 0, 0, 0, 0, 0};
                if (tg >= 0)
                    pk = *reinterpret_cast<const s16x8*>(xin + xbase + (size_t)tg * CH + c8 * 8);
                *reinterpret_cast<s16x8*>(&xs[(size_t)((kk * 8 + c8) * BN + n0 + lane) * 8]) = pk;
            }
        }
    }

    s16x8 w0[6], w1[6];
    {
        const unsigned short* basew = wcpk + ((size_t)(layer * 4 + wv) * 768 + lane) * 8;
        #pragma unroll
        for (int ks = 0; ks < 6; ++ks) {
            w0[ks] = *reinterpret_cast<const s16x8*>(basew + (size_t)ks * 512);
            w1[ks] = *reinterpret_cast<const s16x8*>(basew + (size_t)(6 + ks) * 512);
        }
    }
    const float* Bc = bconv + (size_t)layer * 128;
    float bt[4], bs[4];
    #pragma unroll
    for (int r = 0; r < 4; ++r) {
        bt[r] = Bc[wv * 16 + kgrp * 4 + r];
        bs[r] = Bc[64 + wv * 16 + kgrp * 4 + r];
    }

    __syncthreads();

    f32x4 accT[8], accS[8];
    #pragma unroll
    for (int nt = 0; nt < 8; ++nt) {
        accT[nt] = (f32x4){0.f, 0.f, 0.f, 0.f};
        accS[nt] = (f32x4){0.f, 0.f, 0.f, 0.f};
    }
    #pragma unroll
    for (int nt = 0; nt < 8; ++nt) {
        #pragma unroll
        for (int ks = 0; ks < 6; ++ks) {
            const int kb = ks * 4 + kgrp;
            const unsigned short* bp;
            if (SM == 2) {
                bp = &xs[(size_t)(kb * BN + nt * 16 + hrow) * 8];
            } else {
                const int kk = kb >> 3, c8i = kb & 7;
                bp = &xs[(size_t)(c8i * NW + nt * 16 + hrow + (2 - kk) * dil) * 8];
            }
            const s16x8 bf = *reinterpret_cast<const s16x8*>(bp);
            accT[nt] = __builtin_amdgcn_mfma_f32_16x16x32_bf16(w0[ks], bf, accT[nt], 0, 0, 0);
            accS[nt] = __builtin_amdgcn_mfma_f32_16x16x32_bf16(w1[ks], bf, accS[nt], 0, 0, 0);
        }
    }

    if (!LAST) __syncthreads();

    #pragma unroll
    for (int nt = 0; nt < 8; ++nt) {
        #pragma unroll
        for (int r = 0; r < 4; ++r) {
            const float yt = accT[nt][r] + bt[r];
            const float ys = accS[nt][r] + bs[r];
            const float th = 2.f * __builtin_amdgcn_rcpf(1.f + __expf(-2.f * yt)) - 1.f;
            const float sg = __builtin_amdgcn_rcpf(1.f + __expf(-ys));
            const float av = th * sg;
            const int c = wv * 16 + kgrp * 4 + r;
            const int n = nt * 16 + hrow;
            __builtin_nontemporal_store(av, &skip[xbase + (size_t)c * TLEN + t0 + n]);
            if (LAST) {
                const float res = bf2f(xs[(size_t)((c >> 3) * BN + n) * 8 + (c & 7)]);
                __builtin_nontemporal_store(av + res,
                    &((float*)xout_)[xbase + (size_t)c * TLEN + t0 + n]);
            } else {
                as_[(size_t)((c >> 3) * BN + n) * 8 + (c & 7)] = f2bf(av);
            }
        }
    }

    if (LAST) return;

    __syncthreads();

    s16x8 wa2[2];
    {
        const unsigned short* b2 = wopk + ((size_t)(layer * 4 + wv) * 128 + lane) * 8;
        wa2[0] = *reinterpret_cast<const s16x8*>(b2);
        wa2[1] = *reinterpret_cast<const s16x8*>(b2 + 512);
    }
    const float* Bo = bout + (size_t)layer * CH;
    float bo[4];
    #pragma unroll
    for (int r = 0; r < 4; ++r) bo[r] = Bo[wv * 16 + kgrp * 4 + r];

    const int o0 = wv * 16 + kgrp * 4;
    unsigned short* xout = (unsigned short*)xout_;

    #pragma unroll
    for (int nt = 0; nt < 8; ++nt) {
        f32x4 acc = (f32x4){0.f, 0.f, 0.f, 0.f};
        #pragma unroll
        for (int ks = 0; ks < 2; ++ks) {
            const s16x8 bf = *reinterpret_cast<const s16x8*>(
                &as_[(size_t)((ks * 4 + kgrp) * BN + nt * 16 + hrow) * 8]);
            acc = __builtin_amdgcn_mfma_f32_16x16x32_bf16(wa2[ks], bf, acc, 0, 0, 0);
        }
        const int n = nt * 16 + hrow;
        const u16x4 rv = *reinterpret_cast<const u16x4*>(
            (const unsigned short*)xin_ + xbase + (size_t)(t0 + n) * CH + o0);
        u16x4 ov;
        #pragma unroll
        for (int r = 0; r < 4; ++r) ov[r] = f2bf(acc[r] + bo[r] + bf2f(rv[r]));
        *reinterpret_cast<u16x4*>(&xout[xbase + (size_t)(t0 + n) * CH + o0]) = ov;
    }
}

extern "C" void kernel_launch(void* const* d_in, const int* in_sizes, int n_in,
                              void* d_out, int out_size, void* d_ws, size_t ws_size,
                              hipStream_t stream)
{
    const float* x  = (const float*)d_in[0];
    const float* wc = (const float*)d_in[1];
    const float* bc = (const float*)d_in[2];
    const float* wo = (const float*)d_in[3];
    const float* bo = (const float*)d_in[4];
    float* out = (float*)d_out;
    const size_t planeF = (size_t)NB * CH * TLEN;

    unsigned short* PA = (unsigned short*)d_ws;
    unsigned short* PB = PA + planeF;
    unsigned short* wcpk = PB + planeF;
    unsigned short* wopk = wcpk + NCONV;

    pack_weights<<<(NCONV + NOUT) / 256, 256, 0, stream>>>(wc, wo, wcpk, wopk);

    dim3 grid(TLEN / BN, NB), block(256);

    // fused pairs: (0,1) fp32 input -> PA ; (2,3) PA -> PB ; (4,5) PB -> PA
    wavenet_pair<0, true ><<<grid, block, 0, stream>>>(x,  PA, out, wcpk, wopk, bc, bo);
    wavenet_pair<2, false><<<grid, block, 0, stream>>>(PA, PB, out, wcpk, wopk, bc, bo);
    wavenet_pair<4, false><<<grid, block, 0, stream>>>(PB, PA, out, wcpk, wopk, bc, bo);

    // tails: L6 (d=64, SM1), L7/L8 (SM2), L9 (SM2, LAST -> out slot 0)
    wavenet_layer<1, false><<<grid, block, (size_t)(BN + 128) * 128, stream>>>(
        PA, PB, out + 7 * planeF, wcpk, wopk, bc, bo, 6, 64);
    wavenet_layer<2, false><<<grid, block, 24 * BN * 8 * 2, stream>>>(
        PB, PA, out + 8 * planeF, wcpk, wopk, bc, bo, 7, 128);
    wavenet_layer<2, false><<<grid, block, 24 * BN * 8 * 2, stream>>>(
        PA, PB, out + 9 * planeF, wcpk, wopk, bc, bo, 8, 256);
    wavenet_layer<2, true><<<grid, block, 24 * BN * 8 * 2, stream>>>(
        PB, out, out + 10 * planeF, wcpk, wopk, bc, bo, 9, 512);
}